// Round 8
// baseline (152.604 us; speedup 1.0000x reference)
//
#include <hip/hip_runtime.h>

// Problem constants: B=32, C_IN=64, C_OUT=128, K=3, H=W=128
#define BATCH 32
#define CIN   64
#define COUT  128
#define HW    128
#define OW    126            // H-K+1
#define IMG4  508032         // float4s per batch-image of out (128*126*126/4)

typedef float f4 __attribute__((ext_vector_type(4)));

// ---- Kernel 1: xs[c,h,w] = sum_b x[b,c,h,w]; f4, 4 chains, nt loads ----
__global__ __launch_bounds__(256) void k_bsum(const float* __restrict__ x,
                                              float* __restrict__ xs) {
    const int i = blockIdx.x * blockDim.x + threadIdx.x;   // over 262144 f4s
    const f4* __restrict__ x4 = (const f4*)x;
    const size_t s4 = CIN * HW * HW / 4;                   // 262144 f4 per batch
    f4 a0 = __builtin_nontemporal_load(&x4[i]);
    f4 a1 = __builtin_nontemporal_load(&x4[s4 + i]);
    f4 a2 = __builtin_nontemporal_load(&x4[2 * s4 + i]);
    f4 a3 = __builtin_nontemporal_load(&x4[3 * s4 + i]);
    #pragma unroll
    for (int b = 4; b < BATCH; b += 4) {
        a0 += __builtin_nontemporal_load(&x4[(size_t)b * s4 + i]);
        a1 += __builtin_nontemporal_load(&x4[(size_t)(b + 1) * s4 + i]);
        a2 += __builtin_nontemporal_load(&x4[(size_t)(b + 2) * s4 + i]);
        a3 += __builtin_nontemporal_load(&x4[(size_t)(b + 3) * s4 + i]);
    }
    ((f4*)xs)[i] = (a0 + a1) + (a2 + a3);
}

// ---- Kernel 2: conv(xs, w) + bias -> out batch 0 ONLY (exact R6 config) ----
// x read directly from global (L2/L3-resident) into registers; only weights
// staged in LDS, consumed as wave-uniform b128 broadcasts.
// Tile: 8 rows x 32 cols x 16 oc. Grid (64 spatial, 8 ocg) = 512 blocks.
// Thread: tx=tid&7 (4 px), ty=(tid>>3)&7 (row), og=tid>>6 (4 oc each).
#define OCT 16             // out channels per block
#define ICC 16             // input-channel chunk for weight staging

__global__ __launch_bounds__(256, 2) void k_conv(const float* __restrict__ xs,
                                                 const float* __restrict__ w,
                                                 const float* __restrict__ bias,
                                                 float* __restrict__ out) {
    __shared__ float lw[ICC * 9 * OCT];          // 2304 floats = 9.2 KB

    const int tid  = threadIdx.x;
    const int tile = blockIdx.x;                 // 0..63
    const int ocg  = blockIdx.y;                 // 0..7
    const int row0 = (tile >> 2) * 8;            // 0..120
    const int col0 = (tile & 3) * 32;            // 0,32,64,96
    const int oc0  = ocg * OCT;

    const int tx = tid & 7;
    const int ty = (tid >> 3) & 7;
    const int og = tid >> 6;                     // 0..3 (wave-uniform)

    const int irow = row0 + ty;                  // output row; input rows irow+ky
    const int icol = col0 + tx * 4;              // output col base
    const bool tail = (icol + 5) < HW;           // cols icol+4..5 loadable

    float acc[4][4] = {};                        // [oc][px]

    for (int ic0 = 0; ic0 < CIN; ic0 += ICC) {
        __syncthreads();                         // protect lw from prior readers
        // Stage weight chunk: [(icL*9 + t)*16 + o] <- w[(oc0+o)*576 + (ic0+icL)*9 + t]
        #pragma unroll
        for (int s = tid; s < ICC * 9 * OCT; s += 256) {
            const int o = s & 15;
            const int r = s >> 4;                // icL*9 + t
            lw[s] = w[(oc0 + o) * (CIN * 9) + ic0 * 9 + r];
        }
        __syncthreads();

        #pragma unroll 2
        for (int icL = 0; icL < ICC; ++icL) {
            const float* xb0 = &xs[(((ic0 + icL) * HW) + irow) * HW + icol];
            #pragma unroll
            for (int ky = 0; ky < 3; ++ky) {
                const int gr = irow + ky;
                float xv[6];
                if (gr < HW) {
                    const float4 xa = *(const float4*)(xb0 + ky * HW);
                    xv[0] = xa.x; xv[1] = xa.y; xv[2] = xa.z; xv[3] = xa.w;
                    if (tail) {
                        const float2 xt = *(const float2*)(xb0 + ky * HW + 4);
                        xv[4] = xt.x; xv[5] = xt.y;
                    } else { xv[4] = 0.f; xv[5] = 0.f; }
                } else {
                    xv[0] = xv[1] = xv[2] = xv[3] = xv[4] = xv[5] = 0.f;
                }
                const float* wb = &lw[(icL * 9 + ky * 3) * OCT + og * 4];
                #pragma unroll
                for (int kx = 0; kx < 3; ++kx) {
                    const float4 wv = *(const float4*)(wb + kx * OCT);  // broadcast
                    const float wf[4] = {wv.x, wv.y, wv.z, wv.w};
                    #pragma unroll
                    for (int o = 0; o < 4; ++o)
                        #pragma unroll
                        for (int p = 0; p < 4; ++p)
                            acc[o][p] = fmaf(wf[o], xv[kx + p], acc[o][p]);
                }
            }
        }
    }

    // Bias + write batch 0 only (row pitch 126f -> float2 stores)
    if (irow < OW) {
        #pragma unroll
        for (int o = 0; o < 4; ++o) {
            const int oc = oc0 + og * 4 + o;
            const float bv = bias[oc];
            const float r0 = acc[o][0] + bv, r1 = acc[o][1] + bv;
            const float r2 = acc[o][2] + bv, r3 = acc[o][3] + bv;
            float* op = &out[((size_t)oc * OW + irow) * OW + icol];
            if (icol + 4 <= OW) {
                ((float2*)op)[0] = make_float2(r0, r1);
                ((float2*)op)[1] = make_float2(r2, r3);
            } else {                              // icol == 124: 2 cols left
                ((float2*)op)[0] = make_float2(r0, r1);
            }
        }
    }
}

// ---- Kernel 3: broadcast out[0] -> out[1..31], fill-style flat grid-stride ----
// Dst-linear over 31*IMG4 f4s: dense, line-aligned nt stores (zero write
// amplification, fill-kernel streaming pattern). Src f4 re-read per batch but
// the 8.1 MB source is L2/L3-resident (252 MB of cache reads ~ 7 us at L2 BW).
__global__ __launch_bounds__(256) void k_bcast(float* __restrict__ out) {
    f4* __restrict__ o4 = (f4*)out;
    const unsigned total  = 31u * IMG4;          // 15,748,992
    const unsigned stride = gridDim.x * 256u;
    for (unsigned idx = blockIdx.x * 256u + threadIdx.x; idx < total; idx += stride) {
        const unsigned b = idx / IMG4;           // 0..30 (magic-mul)
        const unsigned r = idx - b * IMG4;
        const f4 v = o4[r];
        __builtin_nontemporal_store(v, &o4[(size_t)(b + 1) * IMG4 + r]);
    }
}

extern "C" void kernel_launch(void* const* d_in, const int* in_sizes, int n_in,
                              void* d_out, int out_size, void* d_ws, size_t ws_size,
                              hipStream_t stream) {
    const float* x    = (const float*)d_in[0];   // [32,64,128,128]
    const float* w    = (const float*)d_in[1];   // [128,64,3,3]
    const float* bias = (const float*)d_in[2];   // [128,1,1]
    float* out = (float*)d_out;                  // [32,128,126,126]
    float* xs  = (float*)d_ws;                   // [64,128,128] scratch (4 MB)

    k_bsum<<<dim3(CIN * HW * HW / 4 / 256), dim3(256), 0, stream>>>(x, xs);
    k_conv<<<dim3(64, 8), dim3(256), 0, stream>>>(xs, w, bias, out);
    k_bcast<<<dim3(3072), dim3(256), 0, stream>>>(out);
}

// Round 9
// 150.146 us; speedup vs baseline: 1.0164x; 1.0164x over previous
//
#include <hip/hip_runtime.h>

// Problem constants: B=32, C_IN=64, C_OUT=128, K=3, H=W=128
#define BATCH 32
#define CIN   64
#define COUT  128
#define HW    128
#define OW    126            // H-K+1
#define IMG   2032128        // floats per batch-image of out (128*126*126)

typedef float f4 __attribute__((ext_vector_type(4)));

// ---- Kernel 1: xs[c,h,w] = sum_b x[b,c,h,w]; f4, 4 chains, nt loads ----
__global__ __launch_bounds__(256) void k_bsum(const float* __restrict__ x,
                                              float* __restrict__ xs) {
    const int i = blockIdx.x * blockDim.x + threadIdx.x;   // over 262144 f4s
    const f4* __restrict__ x4 = (const f4*)x;
    const size_t s4 = CIN * HW * HW / 4;                   // 262144 f4 per batch
    f4 a0 = __builtin_nontemporal_load(&x4[i]);
    f4 a1 = __builtin_nontemporal_load(&x4[s4 + i]);
    f4 a2 = __builtin_nontemporal_load(&x4[2 * s4 + i]);
    f4 a3 = __builtin_nontemporal_load(&x4[3 * s4 + i]);
    #pragma unroll
    for (int b = 4; b < BATCH; b += 4) {
        a0 += __builtin_nontemporal_load(&x4[(size_t)b * s4 + i]);
        a1 += __builtin_nontemporal_load(&x4[(size_t)(b + 1) * s4 + i]);
        a2 += __builtin_nontemporal_load(&x4[(size_t)(b + 2) * s4 + i]);
        a3 += __builtin_nontemporal_load(&x4[(size_t)(b + 3) * s4 + i]);
    }
    ((f4*)xs)[i] = (a0 + a1) + (a2 + a3);
}

// ---- Kernel 2: conv(xs, w) + bias -> ALL 32 batch copies (fused broadcast) ----
// Conv engine identical to R6 (x direct from global/L2, weights in LDS as
// wave-uniform b128 broadcasts). Epilogue writes the register results to all
// 32 batch rows: values are already in registers, so the separate bcast
// kernel (8 MB re-read + kernel gap) disappears.
// Tile: 8 rows x 32 cols x 16 oc. Grid (64 spatial, 8 ocg) = 512 blocks, 2/CU.
#define OCT 16             // out channels per block
#define ICC 16             // input-channel chunk for weight staging

__global__ __launch_bounds__(256, 2) void k_conv(const float* __restrict__ xs,
                                                 const float* __restrict__ w,
                                                 const float* __restrict__ bias,
                                                 float* __restrict__ out) {
    __shared__ float lw[ICC * 9 * OCT];          // 2304 floats = 9.2 KB

    const int tid  = threadIdx.x;
    const int tile = blockIdx.x;                 // 0..63
    const int ocg  = blockIdx.y;                 // 0..7
    const int row0 = (tile >> 2) * 8;            // 0..120
    const int col0 = (tile & 3) * 32;            // 0,32,64,96
    const int oc0  = ocg * OCT;

    const int tx = tid & 7;
    const int ty = (tid >> 3) & 7;
    const int og = tid >> 6;                     // 0..3 (wave-uniform)

    const int irow = row0 + ty;                  // output row; input rows irow+ky
    const int icol = col0 + tx * 4;              // output col base
    const bool tail = (icol + 5) < HW;           // cols icol+4..5 loadable

    float acc[4][4] = {};                        // [oc][px]

    for (int ic0 = 0; ic0 < CIN; ic0 += ICC) {
        __syncthreads();                         // protect lw from prior readers
        // Stage weight chunk: [(icL*9 + t)*16 + o] <- w[(oc0+o)*576 + (ic0+icL)*9 + t]
        #pragma unroll
        for (int s = tid; s < ICC * 9 * OCT; s += 256) {
            const int o = s & 15;
            const int r = s >> 4;                // icL*9 + t
            lw[s] = w[(oc0 + o) * (CIN * 9) + ic0 * 9 + r];
        }
        __syncthreads();

        #pragma unroll 2
        for (int icL = 0; icL < ICC; ++icL) {
            const float* xb0 = &xs[(((ic0 + icL) * HW) + irow) * HW + icol];
            #pragma unroll
            for (int ky = 0; ky < 3; ++ky) {
                const int gr = irow + ky;
                float xv[6];
                if (gr < HW) {
                    const float4 xa = *(const float4*)(xb0 + ky * HW);
                    xv[0] = xa.x; xv[1] = xa.y; xv[2] = xa.z; xv[3] = xa.w;
                    if (tail) {
                        const float2 xt = *(const float2*)(xb0 + ky * HW + 4);
                        xv[4] = xt.x; xv[5] = xt.y;
                    } else { xv[4] = 0.f; xv[5] = 0.f; }
                } else {
                    xv[0] = xv[1] = xv[2] = xv[3] = xv[4] = xv[5] = 0.f;
                }
                const float* wb = &lw[(icL * 9 + ky * 3) * OCT + og * 4];
                #pragma unroll
                for (int kx = 0; kx < 3; ++kx) {
                    const float4 wv = *(const float4*)(wb + kx * OCT);  // broadcast
                    const float wf[4] = {wv.x, wv.y, wv.z, wv.w};
                    #pragma unroll
                    for (int o = 0; o < 4; ++o)
                        #pragma unroll
                        for (int p = 0; p < 4; ++p)
                            acc[o][p] = fmaf(wf[o], xv[kx + p], acc[o][p]);
                }
            }
        }
    }

    // Bias + broadcast-write to ALL 32 batches (row pitch 126f -> float2 stores)
    if (irow < OW) {
        const bool full = (icol + 4 <= OW);       // else icol==124: 2 cols
        float2 v01[4], v23[4];
        #pragma unroll
        for (int o = 0; o < 4; ++o) {
            const float bv = bias[oc0 + og * 4 + o];
            v01[o] = make_float2(acc[o][0] + bv, acc[o][1] + bv);
            v23[o] = make_float2(acc[o][2] + bv, acc[o][3] + bv);
        }
        float* op0 = &out[((size_t)(oc0 + og * 4) * OW + irow) * OW + icol];
        #pragma unroll
        for (int b = 0; b < BATCH; ++b) {
            float* op = op0 + (size_t)b * IMG;    // batch stride = COUT*OW*OW
            #pragma unroll
            for (int o = 0; o < 4; ++o) {
                float* p = op + (size_t)o * (OW * OW);
                ((float2*)p)[0] = v01[o];
                if (full) ((float2*)p)[1] = v23[o];
            }
        }
    }
}

extern "C" void kernel_launch(void* const* d_in, const int* in_sizes, int n_in,
                              void* d_out, int out_size, void* d_ws, size_t ws_size,
                              hipStream_t stream) {
    const float* x    = (const float*)d_in[0];   // [32,64,128,128]
    const float* w    = (const float*)d_in[1];   // [128,64,3,3]
    const float* bias = (const float*)d_in[2];   // [128,1,1]
    float* out = (float*)d_out;                  // [32,128,126,126]
    float* xs  = (float*)d_ws;                   // [64,128,128] scratch (4 MB)

    k_bsum<<<dim3(CIN * HW * HW / 4 / 256), dim3(256), 0, stream>>>(x, xs);
    k_conv<<<dim3(64, 8), dim3(256), 0, stream>>>(xs, w, bias, out);
}

// Round 10
// 121.619 us; speedup vs baseline: 1.2548x; 1.2346x over previous
//
#include <hip/hip_runtime.h>

// Problem constants: B=32, C_IN=64, C_OUT=128, K=3, H=W=128
#define BATCH 32
#define CIN   64
#define COUT  128
#define HW    128
#define OW    126            // H-K+1
#define IMG4  508032         // float4s per batch-image of out (128*126*126/4)

typedef float f4 __attribute__((ext_vector_type(4)));

// ---- Kernel 1: xs[c,h,w] = sum_b x[b,c,h,w]; f4, 4 chains, nt loads ----
__global__ __launch_bounds__(256) void k_bsum(const float* __restrict__ x,
                                              float* __restrict__ xs) {
    const int i = blockIdx.x * blockDim.x + threadIdx.x;   // over 262144 f4s
    const f4* __restrict__ x4 = (const f4*)x;
    const size_t s4 = CIN * HW * HW / 4;                   // 262144 f4 per batch
    f4 a0 = __builtin_nontemporal_load(&x4[i]);
    f4 a1 = __builtin_nontemporal_load(&x4[s4 + i]);
    f4 a2 = __builtin_nontemporal_load(&x4[2 * s4 + i]);
    f4 a3 = __builtin_nontemporal_load(&x4[3 * s4 + i]);
    #pragma unroll
    for (int b = 4; b < BATCH; b += 4) {
        a0 += __builtin_nontemporal_load(&x4[(size_t)b * s4 + i]);
        a1 += __builtin_nontemporal_load(&x4[(size_t)(b + 1) * s4 + i]);
        a2 += __builtin_nontemporal_load(&x4[(size_t)(b + 2) * s4 + i]);
        a3 += __builtin_nontemporal_load(&x4[(size_t)(b + 3) * s4 + i]);
    }
    ((f4*)xs)[i] = (a0 + a1) + (a2 + a3);
}

// ---- Kernel 2: conv(xs, w) + bias -> out batch 0 ONLY ----
// R6 engine + (a) ALL weights staged once in LDS (no main-loop barriers),
// (b) double-buffered register prefetch of x across the ic loop to hide
// L2/L3 latency at 2 waves/SIMD.
// Tile: 8 rows x 32 cols x 16 oc. Grid (64 spatial, 8 ocg) = 512 blocks, 2/CU.
#define OCT 16             // out channels per block

__global__ __launch_bounds__(256, 2) void k_conv(const float* __restrict__ xs,
                                                 const float* __restrict__ w,
                                                 const float* __restrict__ bias,
                                                 float* __restrict__ out) {
    __shared__ float lw[CIN * 9 * OCT];          // 9216 floats = 36.9 KB

    const int tid  = threadIdx.x;
    const int tile = blockIdx.x;                 // 0..63
    const int ocg  = blockIdx.y;                 // 0..7
    const int row0 = (tile >> 2) * 8;            // 0..120
    const int col0 = (tile & 3) * 32;            // 0,32,64,96
    const int oc0  = ocg * OCT;

    const int tx = tid & 7;
    const int ty = (tid >> 3) & 7;
    const int og = tid >> 6;                     // 0..3 (wave-uniform)

    const int irow = row0 + ty;                  // output row; input rows irow+ky
    const int icol = col0 + tx * 4;              // output col base
    const bool tail = (icol + 5) < HW;           // cols icol+4..5 loadable

    // Stage ALL weights once: f4 over w. lw[(r4*4+j)*16 + o] <- w4[(oc0+o)*144 + r4]
    {
        const f4* __restrict__ w4 = (const f4*)w;   // w rows: 576 f = 144 f4
        #pragma unroll
        for (int k = 0; k < 9; ++k) {               // 2304 f4 / 256 threads
            const int s  = tid + k * 256;
            const int o  = s & 15;
            const int r4 = s >> 4;                  // 0..143
            const f4 v = w4[(size_t)(oc0 + o) * 144 + r4];
            lw[(r4 * 4 + 0) * 16 + o] = v.x;
            lw[(r4 * 4 + 1) * 16 + o] = v.y;
            lw[(r4 * 4 + 2) * 16 + o] = v.z;
            lw[(r4 * 4 + 3) * 16 + o] = v.w;
        }
    }
    __syncthreads();                             // the ONLY barrier

    float acc[4][4] = {};                        // [oc][px]

    // x-value register buffers: [ky*6 + j], double-buffered across ic
    float bufA[18], bufB[18];

    const float* xbase = &xs[(size_t)irow * HW + icol];

    // load 18 x-values for input channel ic into buf
    auto loadx = [&](float* buf, int ic) {
        const float* p = xbase + (size_t)ic * (HW * HW);
        #pragma unroll
        for (int ky = 0; ky < 3; ++ky) {
            const int gr = irow + ky;
            if (gr < HW) {
                const float4 xa = *(const float4*)(p + ky * HW);
                buf[ky * 6 + 0] = xa.x; buf[ky * 6 + 1] = xa.y;
                buf[ky * 6 + 2] = xa.z; buf[ky * 6 + 3] = xa.w;
                if (tail) {
                    const float2 xt = *(const float2*)(p + ky * HW + 4);
                    buf[ky * 6 + 4] = xt.x; buf[ky * 6 + 5] = xt.y;
                } else { buf[ky * 6 + 4] = 0.f; buf[ky * 6 + 5] = 0.f; }
            } else {
                #pragma unroll
                for (int j = 0; j < 6; ++j) buf[ky * 6 + j] = 0.f;
            }
        }
    };

    // FMA one input channel from buf against LDS weights (wave-uniform b128)
    auto fmas = [&](const float* buf, int ic) {
        #pragma unroll
        for (int ky = 0; ky < 3; ++ky) {
            const float* wb = &lw[(ic * 9 + ky * 3) * OCT + og * 4];
            #pragma unroll
            for (int kx = 0; kx < 3; ++kx) {
                const float4 wv = *(const float4*)(wb + kx * OCT);  // broadcast
                const float wf[4] = {wv.x, wv.y, wv.z, wv.w};
                #pragma unroll
                for (int o = 0; o < 4; ++o)
                    #pragma unroll
                    for (int p = 0; p < 4; ++p)
                        acc[o][p] = fmaf(wf[o], buf[ky * 6 + kx + p], acc[o][p]);
            }
        }
    };

    loadx(bufA, 0);
    for (int ic = 0; ic < CIN; ic += 2) {        // software pipeline, depth 1
        loadx(bufB, ic + 1);                     // prefetch odd channel
        fmas(bufA, ic);
        if (ic + 2 < CIN) loadx(bufA, ic + 2);   // prefetch next even channel
        fmas(bufB, ic + 1);
    }

    // Bias + write batch 0 only (row pitch 126f -> float2 stores)
    if (irow < OW) {
        #pragma unroll
        for (int o = 0; o < 4; ++o) {
            const int oc = oc0 + og * 4 + o;
            const float bv = bias[oc];
            const float r0 = acc[o][0] + bv, r1 = acc[o][1] + bv;
            const float r2 = acc[o][2] + bv, r3 = acc[o][3] + bv;
            float* op = &out[((size_t)oc * OW + irow) * OW + icol];
            if (icol + 4 <= OW) {
                ((float2*)op)[0] = make_float2(r0, r1);
                ((float2*)op)[1] = make_float2(r2, r3);
            } else {                              // icol == 124: 2 cols left
                ((float2*)op)[0] = make_float2(r0, r1);
            }
        }
    }
}

// ---- Kernel 3: broadcast out[0] -> out[1..31] (exact R6) ----
// Each block loads one 8 KB chunk (512 f4) of batch 0 into registers, then
// stores it to all 31 dst batches: 2 loads, 62 independent wide stores.
__global__ __launch_bounds__(256) void k_bcast(float* __restrict__ out) {
    f4* __restrict__ o4 = (f4*)out;
    const int r0 = blockIdx.x * 512 + threadIdx.x;
    const int r1 = r0 + 256;
    const bool ok0 = r0 < IMG4;
    const bool ok1 = r1 < IMG4;
    f4 v0 = {}; f4 v1 = {};
    if (ok0) v0 = o4[r0];
    if (ok1) v1 = o4[r1];
    #pragma unroll
    for (int b = 1; b < BATCH; ++b) {
        const size_t base = (size_t)b * IMG4;
        if (ok0) o4[base + r0] = v0;
        if (ok1) o4[base + r1] = v1;
    }
}

extern "C" void kernel_launch(void* const* d_in, const int* in_sizes, int n_in,
                              void* d_out, int out_size, void* d_ws, size_t ws_size,
                              hipStream_t stream) {
    const float* x    = (const float*)d_in[0];   // [32,64,128,128]
    const float* w    = (const float*)d_in[1];   // [128,64,3,3]
    const float* bias = (const float*)d_in[2];   // [128,1,1]
    float* out = (float*)d_out;                  // [32,128,126,126]
    float* xs  = (float*)d_ws;                   // [64,128,128] scratch (4 MB)

    k_bsum<<<dim3(CIN * HW * HW / 4 / 256), dim3(256), 0, stream>>>(x, xs);
    k_conv<<<dim3(64, 8), dim3(256), 0, stream>>>(xs, w, bias, out);
    k_bcast<<<dim3((IMG4 + 511) / 512), dim3(256), 0, stream>>>(out);
}